// Round 6
// baseline (91.410 us; speedup 1.0000x reference)
//
#include <hip/hip_runtime.h>
#include <math.h>

// Regular (3,6) QC-LDPC, rate 1/2 (constants from reference).
#define B_     128
#define N_     24576
#define NCOMP_ 4096      // graph decomposes into 4096 independent components
#define ITERS_ 10
#define CLIP_  20.0f
#define NBLOCKS_ ((B_ * NCOMP_) / 256)   // 2048

// Structure proof: edge_to_cn = e/6, edge_to_vn = e%N. CN c owns edges [6c,6c+6).
// For c = k, k+4096, k+8192 those edges map to VNs {6k..6k+5} exactly.
// => component k: CNs {k, k+4096, k+8192}, VNs {6k..6k+5}, 18 edges; fully
// independent of all other components -> whole decode fits in one thread's regs.

__device__ __forceinline__ float clipf(float x) {
    return fminf(fmaxf(x, -CLIP_), CLIP_);   // v_med3_f32
}
__device__ __forceinline__ float clamp0c(float x) {
    return fminf(fmaxf(x, 0.f), CLIP_);      // v_med3_f32 (relu + clip, mag>=0)
}
__device__ __forceinline__ float fmin3(float a, float b, float c) {
    return fminf(fminf(a, b), c);            // v_min3_f32
}
__device__ __forceinline__ float fmed3(float a, float b, float c) {
    return __builtin_amdgcn_fmed3f(a, b, c); // v_med3_f32
}
// Force a wave-uniform value into an SGPR.
__device__ __forceinline__ float rfl(float x) {
    return __uint_as_float(__builtin_amdgcn_readfirstlane(__float_as_uint(x)));
}

// Occupancy history: R3 (256,8) spilled because 40 weight values lived in
// VGPRs. Weights are now readfirstlane'd -> SGPRs; persistent VGPR state is
// ~34 (llr6 + c2v18 + sum6 + 2 accs) with ~20 transients => fits 64-VGPR cap.
// 8 waves/SIMD doubles latency hiding on the c2v->u6->min->c2v dep chain.
// Spill tripwire: WRITE_SIZE jumping +4MB means scratch is back -> revert to 6.
__global__ __launch_bounds__(256, 8) void ldpc_fused_kernel(
    const float* __restrict__ llr_in,     // [B, N]
    const float* __restrict__ cn_weight,  // [ITERS]
    const float* __restrict__ ch_weight,  // [ITERS]
    const float* __restrict__ cn_bias,    // [ITERS]
    float* __restrict__ out,              // [0]=loss (finalize), [1..]=dec [B,N]
    double* __restrict__ partials)        // d_ws: one slot per block, no atomics
{
    const int gid = blockIdx.x * 256 + threadIdx.x;
    const int b = gid >> 12;              // / NCOMP_
    const int k = gid & (NCOMP_ - 1);

    // Per-iteration weights -> SGPRs (uniform).
    float cwv[ITERS_], cnwa[ITERS_], nbias[ITERS_];
    unsigned cnws[ITERS_];
#pragma unroll
    for (int i = 0; i < ITERS_; ++i) {
        float w  = rfl(cn_weight[i]);
        cwv[i]   = rfl(ch_weight[i]);
        cnwa[i]  = fabsf(w);
        cnws[i]  = __float_as_uint(w) & 0x80000000u;
        nbias[i] = -rfl(cn_bias[i]);
    }

    // 6 contiguous channel LLRs for this component (8B-aligned: offset = 24k B)
    const float2* p2 = (const float2*)(llr_in + b * N_ + 6 * k);
    float2 t0 = p2[0], t1 = p2[1], t2 = p2[2];
    float llr[6] = {t0.x, t0.y, t1.x, t1.y, t2.x, t2.y};

    float c2v[3][6];
    float sum[6];
#pragma unroll
    for (int i = 0; i < 6; ++i) {
        sum[i] = 0.f;
        c2v[0][i] = 0.f; c2v[1][i] = 0.f; c2v[2][i] = 0.f;
    }

    float accMax  = 0.f;   // sum of max(-dec,0) terms
    float prodLog = 1.f;   // prod of (1+exp(-|dec|)); 60 terms, each in (1,2]
                           // => product <= 2^60, no overflow; ONE log at end.

#pragma unroll
    for (int it = 0; it < ITERS_; ++it) {
        const float cw = cwv[it];

        // VN totals (shared by the 3 CNs of this component)
        float u6[6];
#pragma unroll
        for (int i = 0; i < 6; ++i) u6[i] = fmaf(llr[i], cw, sum[i]);

#pragma unroll
        for (int cn = 0; cn < 3; ++cn) {
            // v2c = clip(u - c2v); sign bits tracked via float bitcasts (free)
            float t[6];
            unsigned par = cnws[it];       // fold cn_weight sign into parity
#pragma unroll
            for (int j = 0; j < 6; ++j) {
                t[j] = clipf(u6[j] - c2v[cn][j]);
                par ^= __float_as_uint(t[j]);   // only bit31 meaningful
            }
            // Two-min via sorted-triple merge (abs folded as VOP3 modifiers):
            //   m1 = min(minA, minB); m2 = min3(max(minA,minB), medA, medB)
            // Exact incl. ties: dup-min => m2 == m1, so the (a==m1)?m2:m1
            // select below is bit-exact vs the reference m1/m2/cnt form.
            float minA = fmin3(fabsf(t[0]), fabsf(t[1]), fabsf(t[2]));
            float medA = fmed3(fabsf(t[0]), fabsf(t[1]), fabsf(t[2]));
            float minB = fmin3(fabsf(t[3]), fabsf(t[4]), fabsf(t[5]));
            float medB = fmed3(fabsf(t[3]), fabsf(t[4]), fabsf(t[5]));
            float m1 = fminf(minA, minB);
            float m2 = fmin3(fmaxf(minA, minB), medA, medB);
            // Only two possible output magnitudes per CN -> precompute both:
            float M1p = clamp0c(fmaf(m1, cnwa[it], nbias[it]));
            float M2p = clamp0c(fmaf(m2, cnwa[it], nbias[it]));
#pragma unroll
            for (int j = 0; j < 6; ++j) {
                float ext = (fabsf(t[j]) == m1) ? M2p : M1p;  // extrinsic mag
                unsigned sx = par ^ __float_as_uint(t[j]);    // sign of others
                c2v[cn][j] = __uint_as_float((sx & 0x80000000u)
                                             | __float_as_uint(ext));
            }
        }

        // marginals + decision + loss (add order matches reference scatter)
#pragma unroll
        for (int i = 0; i < 6; ++i) {
            sum[i] = (c2v[0][i] + c2v[1][i]) + c2v[2][i];
            float dec = llr[i] + sum[i];
            // softplus(-dec) = max(-dec,0) + log(1+exp(-|dec|));
            // log terms accumulate as a product: p = p*(1+e) = fma(p,e,p).
            accMax  += fmaxf(-dec, 0.f);
            float e  = __expf(-fabsf(dec));
            prodLog  = fmaf(prodLog, e, prodLog);
        }
    }

    // final dec (3 x 8B stores; wave writes 1536 contiguous bytes)
    float2* outd = (float2*)(out + 1 + b * N_ + 6 * k);
    outd[0] = make_float2(llr[0] + sum[0], llr[1] + sum[1]);
    outd[1] = make_float2(llr[2] + sum[2], llr[3] + sum[3]);
    outd[2] = make_float2(llr[4] + sum[4], llr[5] + sum[5]);

    // loss: wave64 shuffle -> LDS -> ONE PLAIN STORE per block (no atomics;
    // R2/R3 were pinned ~105us by 4096 serialized same-address RMWs).
    float local_loss = accMax + __logf(prodLog);
#pragma unroll
    for (int off = 32; off > 0; off >>= 1)
        local_loss += __shfl_down(local_loss, off);
    __shared__ float wsum[4];
    const int lane = threadIdx.x & 63;
    const int wid  = threadIdx.x >> 6;
    if (lane == 0) wsum[wid] = local_loss;
    __syncthreads();
    if (threadIdx.x == 0) {
        double t = ((double)wsum[0] + (double)wsum[1])
                 + ((double)wsum[2] + (double)wsum[3]);
        partials[blockIdx.x] = t;      // distinct address per block
    }
}

__global__ __launch_bounds__(256) void ldpc_finalize_kernel(
    const double* __restrict__ partials,  // [NBLOCKS_]
    float* __restrict__ out)
{
    double s = 0.0;
#pragma unroll
    for (int i = 0; i < NBLOCKS_ / 256; ++i)           // 8 loads/thread
        s += partials[threadIdx.x + 256 * i];
#pragma unroll
    for (int off = 32; off > 0; off >>= 1)
        s += __shfl_down(s, off);
    __shared__ double wsum[4];
    const int lane = threadIdx.x & 63;
    const int wid  = threadIdx.x >> 6;
    if (lane == 0) wsum[wid] = s;
    __syncthreads();
    if (threadIdx.x == 0) {
        double total = (wsum[0] + wsum[1]) + (wsum[2] + wsum[3]);
        out[0] = (float)(total * (1.0 / ((double)B_ * (double)N_)));
    }
}

extern "C" void kernel_launch(void* const* d_in, const int* in_sizes, int n_in,
                              void* d_out, int out_size, void* d_ws, size_t ws_size,
                              hipStream_t stream) {
    const float* llr_in    = (const float*)d_in[0];
    const float* cn_weight = (const float*)d_in[1];
    const float* ch_weight = (const float*)d_in[2];
    const float* cn_bias   = (const float*)d_in[3];
    // d_in[4]/d_in[5] (edge maps) unused: structure is closed-form (e%N, e/6).

    float*  out      = (float*)d_out;
    double* partials = (double*)d_ws;     // 2048 doubles = 16 KB, all overwritten

    ldpc_fused_kernel<<<NBLOCKS_, 256, 0, stream>>>(
        llr_in, cn_weight, ch_weight, cn_bias, out, partials);
    ldpc_finalize_kernel<<<1, 256, 0, stream>>>(partials, out);
}

// Round 7
// 90.015 us; speedup vs baseline: 1.0155x; 1.0155x over previous
//
#include <hip/hip_runtime.h>
#include <math.h>

// Regular (3,6) QC-LDPC, rate 1/2 (constants from reference).
#define B_     128
#define N_     24576
#define NCOMP_ 4096      // graph decomposes into 4096 independent components
#define ITERS_ 10
#define CLIP_  20.0f
#define NBLOCKS_ ((B_ * NCOMP_) / 256)   // 2048

// Structure proof: edge_to_cn = e/6, edge_to_vn = e%N. CN c owns edges [6c,6c+6).
// For c = k, k+4096, k+8192 those edges map to VNs {6k..6k+5} exactly.
// => component k: CNs {k, k+4096, k+8192}, VNs {6k..6k+5}, 18 edges; fully
// independent of all other components -> whole decode fits in one thread's regs.

__device__ __forceinline__ float clipf(float x) {
    return fminf(fmaxf(x, -CLIP_), CLIP_);   // v_med3_f32
}
__device__ __forceinline__ float clamp0c(float x) {
    return fminf(fmaxf(x, 0.f), CLIP_);      // v_med3_f32 (relu + clip, mag>=0)
}
__device__ __forceinline__ float fmin3(float a, float b, float c) {
    return fminf(fminf(a, b), c);            // v_min3_f32
}
__device__ __forceinline__ float fmed3(float a, float b, float c) {
    return __builtin_amdgcn_fmed3f(a, b, c); // v_med3_f32
}
// Force a wave-uniform value into an SGPR.
__device__ __forceinline__ float rfl(float x) {
    return __uint_as_float(__builtin_amdgcn_readfirstlane(__float_as_uint(x)));
}

// Occupancy history: (256,8)/64-VGPR cap regressed twice (R3 hard spill, R6
// mild). (256,6)/85-VGPR cap is the measured best (R5: 89.9us) — keep it.
__global__ __launch_bounds__(256, 6) void ldpc_fused_kernel(
    const float* __restrict__ llr_in,     // [B, N]
    const float* __restrict__ cn_weight,  // [ITERS]
    const float* __restrict__ ch_weight,  // [ITERS]
    const float* __restrict__ cn_bias,    // [ITERS]
    float* __restrict__ out,              // [0]=loss (finalize), [1..]=dec [B,N]
    double* __restrict__ partials)        // d_ws: one slot per block, no atomics
{
    const int gid = blockIdx.x * 256 + threadIdx.x;
    const int b = gid >> 12;              // / NCOMP_
    const int k = gid & (NCOMP_ - 1);

    // Per-iteration weights -> SGPRs (uniform).
    float cwv[ITERS_], cnwa[ITERS_], nbias[ITERS_];
    unsigned cnws[ITERS_];
#pragma unroll
    for (int i = 0; i < ITERS_; ++i) {
        float w  = rfl(cn_weight[i]);
        cwv[i]   = rfl(ch_weight[i]);
        cnwa[i]  = fabsf(w);
        cnws[i]  = __float_as_uint(w) & 0x80000000u;
        nbias[i] = -rfl(cn_bias[i]);
    }

    // 6 contiguous channel LLRs for this component (8B-aligned: offset = 24k B)
    const float2* p2 = (const float2*)(llr_in + b * N_ + 6 * k);
    float2 t0 = p2[0], t1 = p2[1], t2 = p2[2];
    float llr[6] = {t0.x, t0.y, t1.x, t1.y, t2.x, t2.y};

    float c2v[3][6];
    float sum[6];
#pragma unroll
    for (int i = 0; i < 6; ++i) {
        sum[i] = 0.f;
        c2v[0][i] = 0.f; c2v[1][i] = 0.f; c2v[2][i] = 0.f;
    }

    float accMax  = 0.f;   // sum of max(-dec,0) terms
    float prodLog = 1.f;   // prod of (1+exp(-|dec|)); 60 terms, each in (1,2]
                           // => product <= 2^60, no overflow; ONE log at end.

#pragma unroll
    for (int it = 0; it < ITERS_; ++it) {
        const float cw = cwv[it];

        // VN totals (shared by the 3 CNs of this component)
        float u6[6];
#pragma unroll
        for (int i = 0; i < 6; ++i) u6[i] = fmaf(llr[i], cw, sum[i]);

#pragma unroll
        for (int cn = 0; cn < 3; ++cn) {
            // v2c = clip(u - c2v); sign bits tracked via float bitcasts (free)
            float t[6];
            unsigned par = cnws[it];       // fold cn_weight sign into parity
#pragma unroll
            for (int j = 0; j < 6; ++j) {
                t[j] = clipf(u6[j] - c2v[cn][j]);
                par ^= __float_as_uint(t[j]);   // only bit31 meaningful
            }
            // Two-min via sorted-triple merge (abs folded as VOP3 modifiers):
            //   m1 = min(minA, minB); m2 = min3(max(minA,minB), medA, medB)
            // Exact incl. ties: dup-min => m2 == m1, so the (a==m1)?m2:m1
            // select below is bit-exact vs the reference m1/m2/cnt form.
            float minA = fmin3(fabsf(t[0]), fabsf(t[1]), fabsf(t[2]));
            float medA = fmed3(fabsf(t[0]), fabsf(t[1]), fabsf(t[2]));
            float minB = fmin3(fabsf(t[3]), fabsf(t[4]), fabsf(t[5]));
            float medB = fmed3(fabsf(t[3]), fabsf(t[4]), fabsf(t[5]));
            float m1 = fminf(minA, minB);
            float m2 = fmin3(fmaxf(minA, minB), medA, medB);
            // Only two possible output magnitudes per CN -> precompute both:
            float M1p = clamp0c(fmaf(m1, cnwa[it], nbias[it]));
            float M2p = clamp0c(fmaf(m2, cnwa[it], nbias[it]));
#pragma unroll
            for (int j = 0; j < 6; ++j) {
                float ext = (fabsf(t[j]) == m1) ? M2p : M1p;  // extrinsic mag
                unsigned sx = par ^ __float_as_uint(t[j]);    // sign of others
                c2v[cn][j] = __uint_as_float((sx & 0x80000000u)
                                             | __float_as_uint(ext));
            }
        }

        // marginals + decision + loss (add order matches reference scatter)
#pragma unroll
        for (int i = 0; i < 6; ++i) {
            sum[i] = (c2v[0][i] + c2v[1][i]) + c2v[2][i];
            float dec = llr[i] + sum[i];
            // softplus(-dec) = max(-dec,0) + log(1+exp(-|dec|));
            // log terms accumulate as a product: p = p*(1+e) = fma(p,e,p).
            accMax  += fmaxf(-dec, 0.f);
            float e  = __expf(-fabsf(dec));
            prodLog  = fmaf(prodLog, e, prodLog);
        }
    }

    // final dec (3 x 8B stores; wave writes 1536 contiguous bytes)
    float2* outd = (float2*)(out + 1 + b * N_ + 6 * k);
    outd[0] = make_float2(llr[0] + sum[0], llr[1] + sum[1]);
    outd[1] = make_float2(llr[2] + sum[2], llr[3] + sum[3]);
    outd[2] = make_float2(llr[4] + sum[4], llr[5] + sum[5]);

    // loss: wave64 shuffle -> LDS -> ONE PLAIN STORE per block (no atomics;
    // R2/R3 were pinned ~105us by 4096 serialized same-address RMWs).
    float local_loss = accMax + __logf(prodLog);
#pragma unroll
    for (int off = 32; off > 0; off >>= 1)
        local_loss += __shfl_down(local_loss, off);
    __shared__ float wsum[4];
    const int lane = threadIdx.x & 63;
    const int wid  = threadIdx.x >> 6;
    if (lane == 0) wsum[wid] = local_loss;
    __syncthreads();
    if (threadIdx.x == 0) {
        double t = ((double)wsum[0] + (double)wsum[1])
                 + ((double)wsum[2] + (double)wsum[3]);
        partials[blockIdx.x] = t;      // distinct address per block
    }
}

// Single-wave finalize: 64 threads x 32 loads, pure shuffle reduce (no LDS,
// no __syncthreads).
__global__ __launch_bounds__(64) void ldpc_finalize_kernel(
    const double* __restrict__ partials,  // [NBLOCKS_]
    float* __restrict__ out)
{
    double s = 0.0;
#pragma unroll
    for (int i = 0; i < NBLOCKS_ / 64; ++i)            // 32 loads/thread
        s += partials[threadIdx.x + 64 * i];
#pragma unroll
    for (int off = 32; off > 0; off >>= 1)
        s += __shfl_down(s, off);
    if (threadIdx.x == 0)
        out[0] = (float)(s * (1.0 / ((double)B_ * (double)N_)));
}

extern "C" void kernel_launch(void* const* d_in, const int* in_sizes, int n_in,
                              void* d_out, int out_size, void* d_ws, size_t ws_size,
                              hipStream_t stream) {
    const float* llr_in    = (const float*)d_in[0];
    const float* cn_weight = (const float*)d_in[1];
    const float* ch_weight = (const float*)d_in[2];
    const float* cn_bias   = (const float*)d_in[3];
    // d_in[4]/d_in[5] (edge maps) unused: structure is closed-form (e%N, e/6).

    float*  out      = (float*)d_out;
    double* partials = (double*)d_ws;     // 2048 doubles = 16 KB, all overwritten

    ldpc_fused_kernel<<<NBLOCKS_, 256, 0, stream>>>(
        llr_in, cn_weight, ch_weight, cn_bias, out, partials);
    ldpc_finalize_kernel<<<1, 64, 0, stream>>>(partials, out);
}